// Round 1
// baseline (1082.496 us; speedup 1.0000x reference)
//
#include <hip/hip_runtime.h>
#include <hip/hip_bf16.h>
#include <math.h>

#define VOCAB 50257
#define NCLS 20
#define EDIM 64
#define HDIM 64
#define BATCH 128
#define TLEN 2048

typedef float v2f __attribute__((ext_vector_type(2)));

// Static device scratch: no dependence on ws_size, graph-capture safe.
__device__ float g_P[(size_t)2 * VOCAB * 192];   // 77.2 MB, input-projected vocab table (bias folded)
__device__ float g_feats[BATCH * 256];           // pooled features

__device__ __forceinline__ float fast_rcp(float x) { return __builtin_amdgcn_rcpf(x); }

__device__ __forceinline__ float fsigmoid(float x) {
    // 1/(1+exp(-x)); saturates correctly at +-inf
    return fast_rcp(1.f + __expf(-x));
}
__device__ __forceinline__ float ftanh(float x) {
    // 1 - 2/(exp(2x)+1); saturates correctly at +-inf
    float e = __expf(2.f * x);
    return 1.f - 2.f * fast_rcp(e + 1.f);
}

// ---------------- Kernel A: P[dir][v][g] = dot(emb[v], wih[dir][g]) + bih[dir][g] ----------------
__global__ __launch_bounds__(384) void precompute_P(
    const float* __restrict__ emb,
    const float* __restrict__ wih_f, const float* __restrict__ bih_f,
    const float* __restrict__ wih_b, const float* __restrict__ bih_b)
{
    const int t = threadIdx.x;          // 0..383 ; waves are uniform in (dir), contiguous in g
    const int dir = t / 192;
    const int g = t % 192;
    const float* wih = dir ? wih_b : wih_f;
    const float* bih = dir ? bih_b : bih_f;

    float w[64];
#pragma unroll
    for (int e = 0; e < 64; e += 4) {
        float4 v = *(const float4*)(wih + (size_t)g * 64 + e);
        w[e] = v.x; w[e + 1] = v.y; w[e + 2] = v.z; w[e + 3] = v.w;
    }
    const float bias = bih[g];
    float* Pd = g_P + (size_t)dir * VOCAB * 192;

    for (int v = blockIdx.x; v < VOCAB; v += gridDim.x) {
        const float4* er = (const float4*)(emb + (size_t)v * 64);  // wave-uniform address -> scalar loads
        float acc = bias;
#pragma unroll
        for (int e4 = 0; e4 < 16; e4++) {
            float4 x = er[e4];
            acc = fmaf(x.x, w[4 * e4 + 0], acc);
            acc = fmaf(x.y, w[4 * e4 + 1], acc);
            acc = fmaf(x.z, w[4 * e4 + 2], acc);
            acc = fmaf(x.w, w[4 * e4 + 3], acc);
        }
        Pd[(size_t)v * 192 + g] = acc;
    }
}

// ---------------- Kernel B: one wave per (dir, batch) sequence; fused mean/max pooling ----------------
__global__ __launch_bounds__(64, 1) void gru_seq(
    const int* __restrict__ tokens,
    const float* __restrict__ whh_f, const float* __restrict__ bhh_f,
    const float* __restrict__ whh_b, const float* __restrict__ bhh_b)
{
    const int lane = threadIdx.x;        // hidden unit index
    const int blk = blockIdx.x;          // 0..255
    const int b = blk >> 1;
    const int dir = blk & 1;
    const float* whh = dir ? whh_b : whh_f;
    const float* bhh = dir ? bhh_b : bhh_f;
    const float* Pd = g_P + (size_t)dir * VOCAB * 192;

    __shared__ __align__(16) float h_lds[64];
    __shared__ int tok_lds[TLEN];

    // stage token row (8 KB) once
    for (int t = lane; t < TLEN; t += 64) tok_lds[t] = tokens[b * TLEN + t];

    // per-lane whh rows (r,z,n) -> 192 VGPRs as v2f
    v2f wr[32], wz[32], wn[32];
    {
        const float* pr = whh + (size_t)(0 + lane) * 64;
        const float* pz = whh + (size_t)(64 + lane) * 64;
        const float* pn = whh + (size_t)(128 + lane) * 64;
#pragma unroll
        for (int k = 0; k < 16; k++) {
            float4 a = *(const float4*)(pr + 4 * k);
            wr[2 * k] = (v2f){a.x, a.y}; wr[2 * k + 1] = (v2f){a.z, a.w};
            float4 c = *(const float4*)(pz + 4 * k);
            wz[2 * k] = (v2f){c.x, c.y}; wz[2 * k + 1] = (v2f){c.z, c.w};
            float4 d = *(const float4*)(pn + 4 * k);
            wn[2 * k] = (v2f){d.x, d.y}; wn[2 * k + 1] = (v2f){d.z, d.w};
        }
    }
    const float br = bhh[lane], bz = bhh[64 + lane], bn = bhh[128 + lane];

    h_lds[lane] = 0.f;
    float h = 0.f, sum = 0.f, mx = -INFINITY;
    __syncthreads();

    // time mapping: step s -> tt = dir ? T-1-s : s (backward dir feeds reversed sequence)
    auto tok_at = [&](int s) -> int {
        int ss = s < TLEN ? s : TLEN - 1;        // clamp for tail prefetches (values unused)
        return tok_lds[dir ? (TLEN - 1 - ss) : ss];
    };

    // xg prefetch pipeline, depth 3 (~1200 cyc of cover)
    float xrA, xzA, xnA, xrB, xzB, xnB, xrC, xzC, xnC;
    {
        const float* r0 = Pd + (size_t)tok_at(0) * 192;
        xrA = r0[lane]; xzA = r0[64 + lane]; xnA = r0[128 + lane];
        const float* r1 = Pd + (size_t)tok_at(1) * 192;
        xrB = r1[lane]; xzB = r1[64 + lane]; xnB = r1[128 + lane];
        const float* r2 = Pd + (size_t)tok_at(2) * 192;
        xrC = r2[lane]; xzC = r2[64 + lane]; xnC = r2[128 + lane];
    }

    for (int s = 0; s < TLEN; s++) {
        // prefetch step s+3
        const float* rp = Pd + (size_t)tok_at(s + 3) * 192;
        float pxr = rp[lane], pxz = rp[64 + lane], pxn = rp[128 + lane];

        // hg dots over h (LDS broadcast, b128 reads), 2 packed accumulators per gate
        v2f ar0 = {0.f, 0.f}, ar1 = {0.f, 0.f};
        v2f az0 = {0.f, 0.f}, az1 = {0.f, 0.f};
        v2f an0 = {0.f, 0.f}, an1 = {0.f, 0.f};
#pragma unroll
        for (int k = 0; k < 16; k++) {
            float4 h4 = *(const float4*)(h_lds + 4 * k);
            v2f h01 = {h4.x, h4.y}, h23 = {h4.z, h4.w};
            ar0 = __builtin_elementwise_fma(h01, wr[2 * k], ar0);
            az0 = __builtin_elementwise_fma(h01, wz[2 * k], az0);
            an0 = __builtin_elementwise_fma(h01, wn[2 * k], an0);
            ar1 = __builtin_elementwise_fma(h23, wr[2 * k + 1], ar1);
            az1 = __builtin_elementwise_fma(h23, wz[2 * k + 1], az1);
            an1 = __builtin_elementwise_fma(h23, wn[2 * k + 1], an1);
        }
        float hr = (ar0.x + ar0.y) + (ar1.x + ar1.y);
        float hz = (az0.x + az0.y) + (az1.x + az1.y);
        float hn = (an0.x + an0.y) + (an1.x + an1.y);

        float r = fsigmoid(xrA + hr + br);
        float z = fsigmoid(xzA + hz + bz);
        float n = ftanh(xnA + r * (hn + bn));
        h = fmaf(z, h - n, n);               // (1-z)*n + z*h
        sum += h;
        mx = fmaxf(mx, h);

        __syncthreads();                      // all lanes done reading old h (1-wave: cheap)
        h_lds[lane] = h;
        __syncthreads();                      // h visible for next step

        xrA = xrB; xzA = xzB; xnA = xnB;
        xrB = xrC; xzB = xzC; xnB = xnC;
        xrC = pxr; xzC = pxz; xnC = pxn;
    }

    // feats layout [b][256]: [mean_f | mean_b | max_f | max_b]
    g_feats[b * 256 + dir * 64 + lane] = sum * (1.f / TLEN);
    g_feats[b * 256 + 128 + dir * 64 + lane] = mx;
}

// ---------------- Kernel C: classifier  out = W2 @ gelu(W1 @ feats + b1) + b2 ----------------
__global__ __launch_bounds__(64) void classifier(
    const float* __restrict__ w1, const float* __restrict__ b1,
    const float* __restrict__ w2, const float* __restrict__ b2,
    float* __restrict__ out)
{
    const int b = blockIdx.x;
    const int i = threadIdx.x;
    __shared__ float f[256];
    __shared__ float hid[64];
    for (int c = i; c < 256; c += 64) f[c] = g_feats[b * 256 + c];
    __syncthreads();

    float acc = b1[i];
    const float* wrow = w1 + (size_t)i * 256;
#pragma unroll 16
    for (int c = 0; c < 256; c++) acc = fmaf(f[c], wrow[c], acc);
    // exact GELU: x * 0.5 * (1 + erf(x/sqrt(2)))
    hid[i] = acc * 0.5f * (1.f + erff(acc * 0.70710678118654752f));
    __syncthreads();

    if (i < NCLS) {
        float o = b2[i];
        const float* w2r = w2 + (size_t)i * 64;
#pragma unroll
        for (int j = 0; j < 64; j++) o = fmaf(hid[j], w2r[j], o);
        out[b * NCLS + i] = o;
    }
}

extern "C" void kernel_launch(void* const* d_in, const int* in_sizes, int n_in,
                              void* d_out, int out_size, void* d_ws, size_t ws_size,
                              hipStream_t stream) {
    const int*   tokens = (const int*)  d_in[0];
    const float* emb    = (const float*)d_in[1];
    const float* wih_f  = (const float*)d_in[2];
    const float* whh_f  = (const float*)d_in[3];
    const float* bih_f  = (const float*)d_in[4];
    const float* bhh_f  = (const float*)d_in[5];
    const float* wih_b  = (const float*)d_in[6];
    const float* whh_b  = (const float*)d_in[7];
    const float* bih_b  = (const float*)d_in[8];
    const float* bhh_b  = (const float*)d_in[9];
    const float* w1     = (const float*)d_in[10];
    const float* b1     = (const float*)d_in[11];
    const float* w2     = (const float*)d_in[12];
    const float* b2     = (const float*)d_in[13];
    float* out = (float*)d_out;

    precompute_P<<<1024, 384, 0, stream>>>(emb, wih_f, bih_f, wih_b, bih_b);
    gru_seq<<<2 * BATCH, 64, 0, stream>>>(tokens, whh_f, bhh_f, whh_b, bhh_b);
    classifier<<<BATCH, 64, 0, stream>>>(w1, b1, w2, b2, out);
}